// Round 6
// baseline (443.932 us; speedup 1.0000x reference)
//
#include <hip/hip_runtime.h>
#include <hip/hip_bf16.h>

#define N    8192
#define INF  256
#define OUTF 128
#define ALPHA 0.2f

typedef __attribute__((ext_vector_type(8))) short bf16x8;
typedef __attribute__((ext_vector_type(4))) float f32x4;

__device__ __forceinline__ unsigned short f2bf(float x) {
    union { float f; unsigned u; } v; v.f = x;
    unsigned r = v.u + 0x7fff + ((v.u >> 16) & 1);   // RNE
    return (unsigned short)(r >> 16);
}

// async global->LDS, 16 B per lane (wave-uniform LDS base + lane*16)
__device__ __forceinline__ void gll16(const void* g, void* l) {
    __builtin_amdgcn_global_load_lds(
        (const __attribute__((address_space(1))) unsigned*)g,
        (__attribute__((address_space(3))) unsigned*)l, 16, 0, 0);
}

// mask byte from 8 adjacency ints (adj > 0)
__device__ __forceinline__ unsigned pack8(int4 a, int4 b) {
    return (a.x > 0 ?   1u : 0u) | (a.y > 0 ?   2u : 0u)
         | (a.z > 0 ?   4u : 0u) | (a.w > 0 ?   8u : 0u)
         | (b.x > 0 ?  16u : 0u) | (b.y > 0 ?  32u : 0u)
         | (b.z > 0 ?  64u : 0u) | (b.w > 0 ? 128u : 0u);
}

// ---------------- Kernel 1: WhT_b = blocked bf16 (h@W)^T ; f1 ; f2 ----------
__global__ __launch_bounds__(256) void k1_prep(
        const float* __restrict__ h, const float* __restrict__ W,
        const float* __restrict__ a,
        unsigned short* __restrict__ WhTb, float* __restrict__ f1, float* __restrict__ f2) {
    __shared__ float hs[8][INF];          // 8 KB
    const int t = threadIdx.x;

    const int i0 = blockIdx.x * 8;
    #pragma unroll
    for (int u = 0; u < 2; ++u) {
        int idx = u * 256 + t;
        int r   = idx >> 6;
        int kq  = idx & 63;
        *(float4*)&hs[r][kq * 4] = *(const float4*)(h + (size_t)(i0 + r) * INF + kq * 4);
    }
    __syncthreads();

    const int rg = t >> 5;                // 0..7 : row
    const int ct = t & 31;                // 0..31 : col group
    float acc[4] = {0.f, 0.f, 0.f, 0.f};

    #pragma unroll 8
    for (int k = 0; k < INF; ++k) {
        float4 wv = *(const float4*)(W + (size_t)k * OUTF + ct * 4);
        float  hx = hs[rg][k];
        acc[0] += hx * wv.x; acc[1] += hx * wv.y;
        acc[2] += hx * wv.z; acc[3] += hx * wv.w;
    }

    const int r0 = i0 + rg;               // j index
    const int jb = r0 >> 5;
    const int jo = r0 & 31;
    #pragma unroll
    for (int cc = 0; cc < 4; ++cc)
        WhTb[(size_t)jb * 4096 + (ct * 4 + cc) * 32 + jo] = f2bf(acc[cc]);

    const float4 a1v = *(const float4*)(a + ct * 4);
    const float4 a2v = *(const float4*)(a + OUTF + ct * 4);
    float p1 = acc[0]*a1v.x + acc[1]*a1v.y + acc[2]*a1v.z + acc[3]*a1v.w;
    float p2 = acc[0]*a2v.x + acc[1]*a2v.y + acc[2]*a2v.z + acc[3]*a2v.w;
    #pragma unroll
    for (int off = 16; off > 0; off >>= 1) {
        p1 += __shfl_down(p1, off, 32);
        p2 += __shfl_down(p2, off, 32);
    }
    if (ct == 0) { f1[r0] = p1; f2[r0] = p2; }
}

// ---------------- Kernel 2: fused attention, per-wave j-split ---------------
// 256 blocks x 32 rows; 4 waves each own a 2048-j quarter (64 steps) with a
// PRIVATE ring-2 LDS buffer -> zero barriers in the main loop. adj streamed
// directly (bit-pack pass deleted); masks packed from registers with 2-step
// parity prefetch. num/den partials combined through LDS; normalized out
// written directly (k3 + 64 MB num round-trip deleted).
// vmcnt ledger per wave, step jt: [lgkm fence][adj(jt+2)x4][gll(jt+1)x8]
// [f2 ds_read][VALU][wait vmcnt(12)][B ds_read x8][MFMA x16][pack adj(jt+1)].
// Younger-than-gll(jt) at wait = 4 adj + 8 gll = 12 steady; tail 8/0.
// adj(jt+1) is older than gll(jt) => retired by the same wait (no drain).
// lgkm fence at step top: prior-step B reads retired before this step's DMA
// overwrites that ring buffer (same-wave ring-2 hazard).
__device__ __forceinline__ float pbit(float f1r, float fv, unsigned byte_,
                                      int u, float& dsum) {
    float s = f1r + fv;
    float e = fmaxf(s, ALPHA * s);        // leaky-relu, branch-free
    float p = (byte_ & (1u << u)) ? __expf(e) : 0.f;
    dsum += p;
    return p;
}

#define STAGE8(SRC, DST)                                                     \
    gll16((SRC),        (DST));        gll16((SRC) + 1024, (DST) + 1024);    \
    gll16((SRC) + 2048, (DST) + 2048); gll16((SRC) + 3072, (DST) + 3072);    \
    gll16((SRC) + 4096, (DST) + 4096); gll16((SRC) + 5120, (DST) + 5120);    \
    gll16((SRC) + 6144, (DST) + 6144); gll16((SRC) + 7168, (DST) + 7168);

#define STEP(O, JT, VMN, ISSG, ISSA, PACK)                                   \
    {                                                                        \
        asm volatile("s_waitcnt lgkmcnt(0)" ::: "memory");                   \
        if (ISSA) {                                                          \
            const int ai_ = ((JT) + 2) * 8 + quad * 2;                       \
            if ((O) == 0) { eA0 = adjA[ai_]; eA1 = adjA[ai_ + 1];            \
                            eB0 = adjB[ai_]; eB1 = adjB[ai_ + 1]; }          \
            else          { oA0 = adjA[ai_]; oA1 = adjA[ai_ + 1];            \
                            oB0 = adjB[ai_]; oB1 = adjB[ai_ + 1]; }          \
        }                                                                    \
        if (ISSG) {                                                          \
            const char* ws_ = (const char*)WhTb + (size_t)(tbase + (JT) + 1) * 8192 + lsw; \
            char* bd_ = rbase + (((O) ^ 1) ? 8192 : 0);                      \
            STAGE8(ws_, bd_)                                                 \
        }                                                                    \
        float4 F0_ = *(const float4*)&f2s[jw + (JT) * 32 + quad * 8];        \
        float4 F1_ = *(const float4*)&f2s[jw + (JT) * 32 + quad * 8 + 4];    \
        float a0_ = pbit(f1A, F0_.x, byteCA, 0, dsA);                        \
        float a1_ = pbit(f1A, F0_.y, byteCA, 1, dsA);                        \
        float a2_ = pbit(f1A, F0_.z, byteCA, 2, dsA);                        \
        float a3_ = pbit(f1A, F0_.w, byteCA, 3, dsA);                        \
        float a4_ = pbit(f1A, F1_.x, byteCA, 4, dsA);                        \
        float a5_ = pbit(f1A, F1_.y, byteCA, 5, dsA);                        \
        float a6_ = pbit(f1A, F1_.z, byteCA, 6, dsA);                        \
        float a7_ = pbit(f1A, F1_.w, byteCA, 7, dsA);                        \
        float c0_ = pbit(f1B, F0_.x, byteCB, 0, dsB);                        \
        float c1_ = pbit(f1B, F0_.y, byteCB, 1, dsB);                        \
        float c2_ = pbit(f1B, F0_.z, byteCB, 2, dsB);                        \
        float c3_ = pbit(f1B, F0_.w, byteCB, 3, dsB);                        \
        float c4_ = pbit(f1B, F1_.x, byteCB, 4, dsB);                        \
        float c5_ = pbit(f1B, F1_.y, byteCB, 5, dsB);                        \
        float c6_ = pbit(f1B, F1_.z, byteCB, 6, dsB);                        \
        float c7_ = pbit(f1B, F1_.w, byteCB, 7, dsB);                        \
        union { __hip_bfloat162 hh[4]; bf16x8 v; } pkA_, pkB_;               \
        pkA_.hh[0] = __float22bfloat162_rn(make_float2(a0_, a1_));           \
        pkA_.hh[1] = __float22bfloat162_rn(make_float2(a2_, a3_));           \
        pkA_.hh[2] = __float22bfloat162_rn(make_float2(a4_, a5_));           \
        pkA_.hh[3] = __float22bfloat162_rn(make_float2(a6_, a7_));           \
        pkB_.hh[0] = __float22bfloat162_rn(make_float2(c0_, c1_));           \
        pkB_.hh[1] = __float22bfloat162_rn(make_float2(c2_, c3_));           \
        pkB_.hh[2] = __float22bfloat162_rn(make_float2(c4_, c5_));           \
        pkB_.hh[3] = __float22bfloat162_rn(make_float2(c6_, c7_));           \
        bf16x8 afA = pkA_.v, afB = pkB_.v;                                   \
        asm volatile("s_waitcnt vmcnt(" #VMN ")" ::: "memory");              \
        const char* bb_ = rbase + ((O) ? 8192 : 0) + laneb2;                 \
        bf16x8 b0_ = *(const bf16x8*)(bb_);                                  \
        bf16x8 b1_ = *(const bf16x8*)(bb_ + 1024);                           \
        bf16x8 b2_ = *(const bf16x8*)(bb_ + 2048);                           \
        bf16x8 b3_ = *(const bf16x8*)(bb_ + 3072);                           \
        bf16x8 b4_ = *(const bf16x8*)(bb_ + 4096);                           \
        bf16x8 b5_ = *(const bf16x8*)(bb_ + 5120);                           \
        bf16x8 b6_ = *(const bf16x8*)(bb_ + 6144);                           \
        bf16x8 b7_ = *(const bf16x8*)(bb_ + 7168);                           \
        acA0 = __builtin_amdgcn_mfma_f32_16x16x32_bf16(afA, b0_, acA0, 0, 0, 0); \
        acB0 = __builtin_amdgcn_mfma_f32_16x16x32_bf16(afB, b0_, acB0, 0, 0, 0); \
        acA1 = __builtin_amdgcn_mfma_f32_16x16x32_bf16(afA, b1_, acA1, 0, 0, 0); \
        acB1 = __builtin_amdgcn_mfma_f32_16x16x32_bf16(afB, b1_, acB1, 0, 0, 0); \
        acA2 = __builtin_amdgcn_mfma_f32_16x16x32_bf16(afA, b2_, acA2, 0, 0, 0); \
        acB2 = __builtin_amdgcn_mfma_f32_16x16x32_bf16(afB, b2_, acB2, 0, 0, 0); \
        acA3 = __builtin_amdgcn_mfma_f32_16x16x32_bf16(afA, b3_, acA3, 0, 0, 0); \
        acB3 = __builtin_amdgcn_mfma_f32_16x16x32_bf16(afB, b3_, acB3, 0, 0, 0); \
        acA4 = __builtin_amdgcn_mfma_f32_16x16x32_bf16(afA, b4_, acA4, 0, 0, 0); \
        acB4 = __builtin_amdgcn_mfma_f32_16x16x32_bf16(afB, b4_, acB4, 0, 0, 0); \
        acA5 = __builtin_amdgcn_mfma_f32_16x16x32_bf16(afA, b5_, acA5, 0, 0, 0); \
        acB5 = __builtin_amdgcn_mfma_f32_16x16x32_bf16(afB, b5_, acB5, 0, 0, 0); \
        acA6 = __builtin_amdgcn_mfma_f32_16x16x32_bf16(afA, b6_, acA6, 0, 0, 0); \
        acB6 = __builtin_amdgcn_mfma_f32_16x16x32_bf16(afB, b6_, acB6, 0, 0, 0); \
        acA7 = __builtin_amdgcn_mfma_f32_16x16x32_bf16(afA, b7_, acA7, 0, 0, 0); \
        acB7 = __builtin_amdgcn_mfma_f32_16x16x32_bf16(afB, b7_, acB7, 0, 0, 0); \
        if (PACK) {                                                          \
            if ((O) == 0) { byteCA = pack8(oA0, oA1); byteCB = pack8(oB0, oB1); } \
            else          { byteCA = pack8(eA0, eA1); byteCB = pack8(eB0, eB1); } \
        }                                                                    \
    }

__global__ __launch_bounds__(256, 1) void k2_attn(
        const int* __restrict__ adj, const unsigned short* __restrict__ WhTb,
        const float* __restrict__ f1, const float* __restrict__ f2,
        float* __restrict__ out) {
    // [0,64K): 4 waves x (2 x 8 KB ring); reused as numl[w][32][128] epilogue
    // [64K,96K): f2s (8192 f32); head 512 B reused as denl[4][32] epilogue
    __shared__ __align__(16) char smem[98304];
    float* f2s = (float*)(smem + 65536);

    const int t    = threadIdx.x;             // 0..255 (4 waves)
    const int wv   = t >> 6;                  // wave -> j-quarter
    const int ln   = t & 63;
    const int m16  = ln & 15;
    const int quad = ln >> 4;
    const int i0   = blockIdx.x * 32;
    const int rowA = i0 + m16;
    const int rowB = i0 + 16 + m16;
    const int jw   = wv * 2048;               // wave's j-base (f2s float idx)
    const int tbase = wv * 64;                // wave's first 32-j tile
    char* rbase = smem + wv * 16384;          // wave's private ring
    const int laneb2 = m16 * 64 + ((quad ^ ((m16 >> 1) & 3)) << 4);
    const int lsw = (ln * 16) ^ (((ln >> 3) & 3) << 4);

    // stage f2 cooperatively, sync BEFORE any pipeline issues (no drain later)
    {
        const float4* f2g4 = (const float4*)f2;
        float4* f2s4 = (float4*)f2s;
        #pragma unroll
        for (int u = 0; u < 8; ++u) f2s4[u * 256 + t] = f2g4[u * 256 + t];
    }
    const float f1A = f1[rowA];
    const float f1B = f1[rowB];
    __syncthreads();

    // per-wave prologue: adj(0) consumed now, adj(1)->odd set, tile 0 staged
    const int4* adjA = (const int4*)(adj + (size_t)rowA * N + jw);
    const int4* adjB = (const int4*)(adj + (size_t)rowB * N + jw);
    int4 eA0 = {}, eA1 = {}, eB0 = {}, eB1 = {};
    int4 pA0 = adjA[quad * 2], pA1 = adjA[quad * 2 + 1];
    int4 pB0 = adjB[quad * 2], pB1 = adjB[quad * 2 + 1];
    int4 oA0 = adjA[8 + quad * 2], oA1 = adjA[8 + quad * 2 + 1];
    int4 oB0 = adjB[8 + quad * 2], oB1 = adjB[8 + quad * 2 + 1];
    {
        const char* ws0 = (const char*)WhTb + (size_t)tbase * 8192 + lsw;
        STAGE8(ws0, rbase)
    }
    unsigned byteCA = pack8(pA0, pA1);
    unsigned byteCB = pack8(pB0, pB1);

    f32x4 acA0 = {0.f,0.f,0.f,0.f}, acA1 = {0.f,0.f,0.f,0.f};
    f32x4 acA2 = {0.f,0.f,0.f,0.f}, acA3 = {0.f,0.f,0.f,0.f};
    f32x4 acA4 = {0.f,0.f,0.f,0.f}, acA5 = {0.f,0.f,0.f,0.f};
    f32x4 acA6 = {0.f,0.f,0.f,0.f}, acA7 = {0.f,0.f,0.f,0.f};
    f32x4 acB0 = {0.f,0.f,0.f,0.f}, acB1 = {0.f,0.f,0.f,0.f};
    f32x4 acB2 = {0.f,0.f,0.f,0.f}, acB3 = {0.f,0.f,0.f,0.f};
    f32x4 acB4 = {0.f,0.f,0.f,0.f}, acB5 = {0.f,0.f,0.f,0.f};
    f32x4 acB6 = {0.f,0.f,0.f,0.f}, acB7 = {0.f,0.f,0.f,0.f};
    float dsA = 0.f, dsB = 0.f;

    for (int g = 0; g < 31; ++g) {
        const int jt = g * 2;
        STEP(0, jt,     12, 1, 1, 1)
        STEP(1, jt + 1, 12, 1, 1, 1)
    }
    STEP(0, 62, 8, 1, 0, 1)
    STEP(1, 63, 0, 0, 0, 0)

    // epilogue: num partial -> own ring region (private, no barrier needed)
    float* nl = (float*)rbase;                // [32][128]
    #pragma unroll
    for (int r = 0; r < 4; ++r) {
        const int ra = quad * 4 + r;
        nl[ra * 128 + 0 * 16 + m16] = acA0[r];
        nl[ra * 128 + 1 * 16 + m16] = acA1[r];
        nl[ra * 128 + 2 * 16 + m16] = acA2[r];
        nl[ra * 128 + 3 * 16 + m16] = acA3[r];
        nl[ra * 128 + 4 * 16 + m16] = acA4[r];
        nl[ra * 128 + 5 * 16 + m16] = acA5[r];
        nl[ra * 128 + 6 * 16 + m16] = acA6[r];
        nl[ra * 128 + 7 * 16 + m16] = acA7[r];
        nl[(16 + ra) * 128 + 0 * 16 + m16] = acB0[r];
        nl[(16 + ra) * 128 + 1 * 16 + m16] = acB1[r];
        nl[(16 + ra) * 128 + 2 * 16 + m16] = acB2[r];
        nl[(16 + ra) * 128 + 3 * 16 + m16] = acB3[r];
        nl[(16 + ra) * 128 + 4 * 16 + m16] = acB4[r];
        nl[(16 + ra) * 128 + 5 * 16 + m16] = acB5[r];
        nl[(16 + ra) * 128 + 6 * 16 + m16] = acB6[r];
        nl[(16 + ra) * 128 + 7 * 16 + m16] = acB7[r];
    }
    dsA += __shfl_xor(dsA, 16); dsA += __shfl_xor(dsA, 32);
    dsB += __shfl_xor(dsB, 16); dsB += __shfl_xor(dsB, 32);
    __syncthreads();                          // all waves done with f2s+rings
    float* denl = f2s;                        // reuse head 512 B
    if (quad == 0) {
        denl[wv * 32 + m16]      = dsA;
        denl[wv * 32 + 16 + m16] = dsB;
    }
    __syncthreads();

    const int row = t >> 3;                   // 0..31
    const int c0  = (t & 7) * 16;
    const float den = denl[row] + denl[32 + row] + denl[64 + row] + denl[96 + row];
    const float inv = 1.0f / den;
    float* op = out + (size_t)(i0 + row) * OUTF + c0;
    #pragma unroll
    for (int k = 0; k < 4; ++k) {
        float4 sv = {0.f, 0.f, 0.f, 0.f};
        #pragma unroll
        for (int w = 0; w < 4; ++w) {
            const float4 v = *(const float4*)((const float*)(smem + w * 16384) + row * 128 + c0 + k * 4);
            sv.x += v.x; sv.y += v.y; sv.z += v.z; sv.w += v.w;
        }
        float4 o = {sv.x * inv, sv.y * inv, sv.z * inv, sv.w * inv};
        *(float4*)(op + k * 4) = o;
    }
}

extern "C" void kernel_launch(void* const* d_in, const int* in_sizes, int n_in,
                              void* d_out, int out_size, void* d_ws, size_t ws_size,
                              hipStream_t stream) {
    const float* h   = (const float*)d_in[0];   // (8192, 256)
    const int*   adj = (const int*)  d_in[1];   // (8192, 8192)
    const float* W   = (const float*)d_in[2];   // (256, 128)
    const float* a   = (const float*)d_in[3];   // (256, 1)
    float* out = (float*)d_out;                 // (8192, 128)

    unsigned short* WhTb = (unsigned short*)d_ws;          // 2 MB blocked bf16
    float* f1 = (float*)(WhTb + (size_t)N * OUTF);         // 32 KB
    float* f2 = f1 + N;                                    // 32 KB

    k1_prep <<<N / 8, 256, 0, stream>>>(h, W, a, WhTb, f1, f2);
    k2_attn <<<N / 32, 256, 0, stream>>>(adj, WhTb, f1, f2, out);
}